// Round 13
// baseline (238.302 us; speedup 1.0000x reference)
//
#include <hip/hip_runtime.h>

// Problem constants (fixed by setup_inputs)
#define B_   8
#define C_   64
#define O_   64
#define H_   128
#define W_   128
#define HO_  128
#define WO_  128
#define K2_  9
#define MOFF 18          // 2*K*K offset channels
#define PLANE (H_*W_)    // 16384
#define KTOT 576         // C_*K2_

typedef short bf16x8 __attribute__((ext_vector_type(8)));
typedef float f32x16 __attribute__((ext_vector_type(16)));

__device__ __forceinline__ unsigned short f2bf(float f) {
    // round-to-nearest-even fp32 -> bf16
    unsigned u = __float_as_uint(f);
    u += 0x7fff + ((u >> 16) & 1);
    return (unsigned short)(u >> 16);
}
__device__ __forceinline__ float bf2f(short v) {
    return __uint_as_float(((unsigned)(unsigned short)v) << 16);
}

// ---------------------------------------------------------------------------
// PREP (merged): blocks [0,1024): NHWC chunk-major transpose of x;
//                blocks [1024,1168): cvt_w; blocks [1168,1240): cvt_woff.
// Layouts identical to R12-verified versions:
//   xt[((cc*B + b)*PLANE + y*W + px)*16 + cl] = bf16(x[b][cc*16+cl][y][px])
//   wbf[o*576 + cc*144 + t*16 + cl]  = bf16(w[o][cc*16+cl][t])
//   wobf[o*576 + cc*144 + t*16 + cl] = bf16(w_off[o][cc*16+cl][t]), o>=18 -> 0
// ---------------------------------------------------------------------------
__global__ __launch_bounds__(256) void prep_kernel(const float* __restrict__ x,
        const float* __restrict__ w, const float* __restrict__ w_off,
        unsigned short* __restrict__ xt, unsigned short* __restrict__ wbf,
        unsigned short* __restrict__ wobf) {
    __shared__ unsigned short T[64 * 130];
    const int tid = threadIdx.x;
    const int bid = blockIdx.x;
    if (bid < 1024) {
        const int b = bid & 7;
        const int y = bid >> 3;
        const float* src = x + (size_t)b * C_ * PLANE + y * W_;
        for (int i = tid; i < 64 * 128; i += 256) {
            int c = i >> 7, px = i & 127;
            T[c * 130 + px] = f2bf(src[c * PLANE + px]);
        }
        __syncthreads();
        for (int j = tid; j < 128 * 4; j += 256) {
            int cc = j >> 7, px = j & 127;
            unsigned short* dst = xt + ((size_t)(cc * B_ + b) * PLANE + y * W_ + px) * 16;
            ushort4 v0 = { T[(cc*16+ 0)*130+px], T[(cc*16+ 1)*130+px],
                           T[(cc*16+ 2)*130+px], T[(cc*16+ 3)*130+px] };
            ushort4 v1 = { T[(cc*16+ 4)*130+px], T[(cc*16+ 5)*130+px],
                           T[(cc*16+ 6)*130+px], T[(cc*16+ 7)*130+px] };
            ushort4 v2 = { T[(cc*16+ 8)*130+px], T[(cc*16+ 9)*130+px],
                           T[(cc*16+10)*130+px], T[(cc*16+11)*130+px] };
            ushort4 v3 = { T[(cc*16+12)*130+px], T[(cc*16+13)*130+px],
                           T[(cc*16+14)*130+px], T[(cc*16+15)*130+px] };
            *(ushort4*)(dst)      = v0;
            *(ushort4*)(dst + 4)  = v1;
            *(ushort4*)(dst + 8)  = v2;
            *(ushort4*)(dst + 12) = v3;
        }
    } else if (bid < 1024 + 144) {
        int i = (bid - 1024) * 256 + tid;       // 64*576 = 36864
        if (i < O_ * KTOT) {
            int o = i / KTOT, pos = i % KTOT;
            int cc = pos / 144, r = pos % 144, t = r / 16, cl = r % 16;
            wbf[i] = f2bf(w[o * KTOT + (cc * 16 + cl) * 9 + t]);
        }
    } else {
        int i = (bid - 1024 - 144) * 256 + tid; // 32*576 = 18432
        if (i < 32 * KTOT) {
            int o = i / KTOT, pos = i % KTOT;
            int cc = pos / 144, r = pos % 144, t = r / 16, cl = r % 16;
            wobf[i] = (o < MOFF) ? f2bf(w_off[o * KTOT + (cc * 16 + cl) * 9 + t])
                                 : (unsigned short)0;
        }
    }
}

// ---------------------------------------------------------------------------
// FUSED offset-conv + deformable-conv — BARRIER-FREE main loops.
// Block = (b,ho), 4 waves; wave wv owns pixels [wv*32, wv*32+32) end-to-end.
// MFMA 32x32x16 B-fragment lane mapping: n = lane&31 (pixel), k-half = lane>>5
// (channels kh*8..+8) -> each lane builds its own B-fragment in REGISTERS:
//   Phase A (offset conv, M=32 x N=32/wave): B-frag = direct global bf16x8
//     load of the regular tap (row-OOB -> skip MFMA; col-OOB -> zero frag).
//     Epilogue -> lo[18][128] in LDS (written & read by the same wave).
//   Phase B (deform conv, M=64 x N=32/wave): B-frag = 4-corner bilinear blend
//     in registers (identical math to R12's ls path); 2 accs (mbase 0/32).
// LDS = lo only (9,216 B); no __syncthreads in any loop.
// ---------------------------------------------------------------------------
__global__ __launch_bounds__(256, 4) void fused_kernel(const unsigned short* __restrict__ xt,
        const unsigned short* __restrict__ wobf, const float* __restrict__ b_off,
        const unsigned short* __restrict__ wbf, const float* __restrict__ bias,
        float* __restrict__ out) {
    __shared__ float lo[MOFF * 128];            // 9,216 B
    const int tid  = threadIdx.x;
    const int id   = blockIdx.x;                // 1024
    const int b    = id & 7;
    const int ho   = id >> 3;
    const int lane = tid & 63;
    const int wv   = tid >> 6;
    const int m    = lane & 31;
    const int kh   = lane >> 5;                 // k-half: channels kh*8..+8
    const int px_i = (wv << 5) + m;             // this lane's pixel (= wo)

    // ================= Phase A: offset conv (M=32 x N=32 per wave) =========
    {
        f32x16 acc = {};
        for (int cc = 0; cc < 4; ++cc) {
            const unsigned short* xtc = xt + (size_t)(cc * B_ + b) * PLANE * 16;
            #pragma unroll
            for (int ks = 0; ks < 9; ++ks) {
                const int y = ho - 1 + ks / 3;
                if ((unsigned)y >= (unsigned)H_) continue;   // wave-uniform
                const int xx = px_i - 1 + ks % 3;
                bf16x8 bfr = {};
                if ((unsigned)xx < (unsigned)W_)
                    bfr = *(const bf16x8*)&xtc[(y * W_ + xx) * 16 + kh * 8];
                bf16x8 a = *(const bf16x8*)&wobf[m * KTOT + cc * 144 + ks * 16 + kh * 8];
                acc = __builtin_amdgcn_mfma_f32_32x32x16_bf16(a, bfr, acc, 0, 0, 0);
            }
        }
        // epilogue -> lo (cols = this wave's pixels only)
        #pragma unroll
        for (int r = 0; r < 16; ++r) {
            int mo = (r & 3) + ((r >> 2) << 3) + (kh << 2);
            if (mo < MOFF) lo[mo * 128 + px_i] = acc[r] + b_off[mo];
        }
    }
    __syncthreads();    // formal safety for cross-half-wave lo visibility

    // ================= Phase B: deform conv (M=64 x N=32 per wave) =========
    float py_r[9], px_r[9];
    #pragma unroll
    for (int t = 0; t < 9; ++t) {
        py_r[t] = (float)(ho - 1 + t / 3) + lo[(2 * t) * 128 + px_i];
        px_r[t] = (float)(px_i - 1 + t % 3) + lo[(2 * t + 1) * 128 + px_i];
    }

    f32x16 acc[2] = {};
    for (int cc = 0; cc < 4; ++cc) {
        const unsigned short* xtc = xt + (size_t)(cc * B_ + b) * PLANE * 16;
        #pragma unroll
        for (int ks = 0; ks < 9; ++ks) {
            float py = py_r[ks], px = px_r[ks];
            float fy = floorf(py), fx = floorf(px);
            float wy = py - fy,    wx = px - fx;
            int y0 = (int)fy, x0 = (int)fx;
            float s[8];
            #pragma unroll
            for (int j = 0; j < 8; ++j) s[j] = 0.f;
            #pragma unroll
            for (int c2 = 0; c2 < 4; ++c2) {
                int yy = y0 + (c2 >> 1);
                int xx = x0 + (c2 & 1);
                bool valid = ((unsigned)yy < (unsigned)H_) && ((unsigned)xx < (unsigned)W_);
                int yc = min(max(yy, 0), H_ - 1);
                int xc = min(max(xx, 0), W_ - 1);
                float wgt = ((c2 >> 1) ? wy : 1.f - wy) * ((c2 & 1) ? wx : 1.f - wx);
                wgt = valid ? wgt : 0.f;
                bf16x8 u = *(const bf16x8*)&xtc[(yc * W_ + xc) * 16 + kh * 8];
                #pragma unroll
                for (int j = 0; j < 8; ++j) s[j] += wgt * bf2f(u[j]);
            }
            bf16x8 v;
            #pragma unroll
            for (int j = 0; j < 8; ++j) v[j] = (short)f2bf(s[j]);
            bf16x8 a0 = *(const bf16x8*)&wbf[m * KTOT + cc * 144 + ks * 16 + kh * 8];
            bf16x8 a1 = *(const bf16x8*)&wbf[(32 + m) * KTOT + cc * 144 + ks * 16 + kh * 8];
            acc[0] = __builtin_amdgcn_mfma_f32_32x32x16_bf16(a0, v, acc[0], 0, 0, 0);
            acc[1] = __builtin_amdgcn_mfma_f32_32x32x16_bf16(a1, v, acc[1], 0, 0, 0);
        }
    }

    // epilogue: col = this lane's pixel, rows = out channels (32x32 layout)
    float* op = out + (size_t)b * O_ * PLANE + ho * WO_ + px_i;
    #pragma unroll
    for (int nt = 0; nt < 2; ++nt) {
        #pragma unroll
        for (int r = 0; r < 16; ++r) {
            int mo = (nt << 5) + (r & 3) + ((r >> 2) << 3) + (kh << 2);
            __builtin_nontemporal_store(acc[nt][r] + bias[mo], op + (size_t)mo * PLANE);
        }
    }
}

// ---------------------------------------------------------------------------
extern "C" void kernel_launch(void* const* d_in, const int* in_sizes, int n_in,
                              void* d_out, int out_size, void* d_ws, size_t ws_size,
                              hipStream_t stream) {
    const float* x     = (const float*)d_in[0];
    const float* w_off = (const float*)d_in[1];
    const float* b_off = (const float*)d_in[2];
    const float* w     = (const float*)d_in[3];
    const float* bias  = (const float*)d_in[4];
    float* out = (float*)d_out;

    unsigned short* wbf  = (unsigned short*)d_ws;                   // 72 KB (tap-major)
    unsigned short* wobf = wbf + O_ * KTOT;                         // 36 KB (tap-major)
    unsigned short* xt   = wobf + 32 * KTOT;                        // 16.78 MB chunk-major

    prep_kernel <<<1024 + 144 + 72, 256, 0, stream>>>(x, w, w_off, xt, wbf, wobf);
    fused_kernel<<<B_ * HO_, 256, 0, stream>>>(xt, wobf, b_off, wbf, bias, out);
}

// Round 14
// 237.779 us; speedup vs baseline: 1.0022x; 1.0022x over previous
//
#include <hip/hip_runtime.h>

// Problem constants (fixed by setup_inputs)
#define B_   8
#define C_   64
#define O_   64
#define H_   128
#define W_   128
#define HO_  128
#define WO_  128
#define K2_  9
#define MOFF 18          // 2*K*K offset channels
#define PLANE (H_*W_)    // 16384
#define KTOT 576         // C_*K2_

typedef short bf16x8 __attribute__((ext_vector_type(8)));
typedef float f32x16 __attribute__((ext_vector_type(16)));

__device__ __forceinline__ unsigned short f2bf(float f) {
    // round-to-nearest-even fp32 -> bf16
    unsigned u = __float_as_uint(f);
    u += 0x7fff + ((u >> 16) & 1);
    return (unsigned short)(u >> 16);
}
__device__ __forceinline__ float bf2f(short v) {
    return __uint_as_float(((unsigned)(unsigned short)v) << 16);
}

// ---------------------------------------------------------------------------
// PREP (merged): blocks [0,1024): NHWC chunk-major transpose of x;
//                blocks [1024,1168): cvt_w; blocks [1168,1240): cvt_woff.
//   xt[((cc*B + b)*PLANE + y*W + px)*16 + cl] = bf16(x[b][cc*16+cl][y][px])
//   wbf[o*576 + cc*144 + t*16 + cl]  = bf16(w[o][cc*16+cl][t])
//   wobf[o*576 + cc*144 + t*16 + cl] = bf16(w_off[o][cc*16+cl][t]), o>=18 -> 0
// ---------------------------------------------------------------------------
__global__ __launch_bounds__(256) void prep_kernel(const float* __restrict__ x,
        const float* __restrict__ w, const float* __restrict__ w_off,
        unsigned short* __restrict__ xt, unsigned short* __restrict__ wbf,
        unsigned short* __restrict__ wobf) {
    __shared__ unsigned short T[64 * 130];
    const int tid = threadIdx.x;
    const int bid = blockIdx.x;
    if (bid < 1024) {
        const int b = bid & 7;
        const int y = bid >> 3;
        const float* src = x + (size_t)b * C_ * PLANE + y * W_;
        for (int i = tid; i < 64 * 128; i += 256) {
            int c = i >> 7, px = i & 127;
            T[c * 130 + px] = f2bf(src[c * PLANE + px]);
        }
        __syncthreads();
        for (int j = tid; j < 128 * 4; j += 256) {
            int cc = j >> 7, px = j & 127;
            unsigned short* dst = xt + ((size_t)(cc * B_ + b) * PLANE + y * W_ + px) * 16;
            ushort4 v0 = { T[(cc*16+ 0)*130+px], T[(cc*16+ 1)*130+px],
                           T[(cc*16+ 2)*130+px], T[(cc*16+ 3)*130+px] };
            ushort4 v1 = { T[(cc*16+ 4)*130+px], T[(cc*16+ 5)*130+px],
                           T[(cc*16+ 6)*130+px], T[(cc*16+ 7)*130+px] };
            ushort4 v2 = { T[(cc*16+ 8)*130+px], T[(cc*16+ 9)*130+px],
                           T[(cc*16+10)*130+px], T[(cc*16+11)*130+px] };
            ushort4 v3 = { T[(cc*16+12)*130+px], T[(cc*16+13)*130+px],
                           T[(cc*16+14)*130+px], T[(cc*16+15)*130+px] };
            *(ushort4*)(dst)      = v0;
            *(ushort4*)(dst + 4)  = v1;
            *(ushort4*)(dst + 8)  = v2;
            *(ushort4*)(dst + 12) = v3;
        }
    } else if (bid < 1024 + 144) {
        int i = (bid - 1024) * 256 + tid;       // 64*576 = 36864
        if (i < O_ * KTOT) {
            int o = i / KTOT, pos = i % KTOT;
            int cc = pos / 144, r = pos % 144, t = r / 16, cl = r % 16;
            wbf[i] = f2bf(w[o * KTOT + (cc * 16 + cl) * 9 + t]);
        }
    } else {
        int i = (bid - 1024 - 144) * 256 + tid; // 32*576 = 18432
        if (i < 32 * KTOT) {
            int o = i / KTOT, pos = i % KTOT;
            int cc = pos / 144, r = pos % 144, t = r / 16, cl = r % 16;
            wobf[i] = (o < MOFF) ? f2bf(w_off[o * KTOT + (cc * 16 + cl) * 9 + t])
                                 : (unsigned short)0;
        }
    }
}

// ---------------------------------------------------------------------------
// FUSED offset-conv + deformable-conv — BARRIER-FREE main loops (R13 body).
// __launch_bounds__(256,3): compiler gets ~84+ VGPRs -> NO scratch spill
// (the (256,4) build clamps to 64 regs and spills the phase-B loop — R13's
// +120 MB symmetric FETCH/WRITE regression).
// Block = (b,ho), 4 waves; wave wv owns pixels [wv*32, wv*32+32) end-to-end.
// B-fragment lane mapping (32x32x16): n = lane&31 (pixel), k-half = lane>>5.
// Phase A: B-frag = direct global bf16x8 load of the regular tap.
// Phase B: B-frag = 4-corner bilinear blend in registers.
// LDS = lo only (9,216 B); one barrier between phases.
// ---------------------------------------------------------------------------
__global__ __launch_bounds__(256, 3) void fused_kernel(const unsigned short* __restrict__ xt,
        const unsigned short* __restrict__ wobf, const float* __restrict__ b_off,
        const unsigned short* __restrict__ wbf, const float* __restrict__ bias,
        float* __restrict__ out) {
    __shared__ float lo[MOFF * 128];            // 9,216 B
    const int tid  = threadIdx.x;
    const int id   = blockIdx.x;                // 1024
    const int b    = id & 7;
    const int ho   = id >> 3;
    const int lane = tid & 63;
    const int wv   = tid >> 6;
    const int m    = lane & 31;
    const int kh   = lane >> 5;                 // k-half: channels kh*8..+8
    const int px_i = (wv << 5) + m;             // this lane's pixel (= wo)

    // ================= Phase A: offset conv (M=32 x N=32 per wave) =========
    {
        f32x16 acc = {};
        for (int cc = 0; cc < 4; ++cc) {
            const unsigned short* xtc = xt + (size_t)(cc * B_ + b) * PLANE * 16;
            #pragma unroll
            for (int ks = 0; ks < 9; ++ks) {
                const int y = ho - 1 + ks / 3;
                if ((unsigned)y >= (unsigned)H_) continue;   // wave-uniform
                const int xx = px_i - 1 + ks % 3;
                bf16x8 bfr = {};
                if ((unsigned)xx < (unsigned)W_)
                    bfr = *(const bf16x8*)&xtc[(y * W_ + xx) * 16 + kh * 8];
                bf16x8 a = *(const bf16x8*)&wobf[m * KTOT + cc * 144 + ks * 16 + kh * 8];
                acc = __builtin_amdgcn_mfma_f32_32x32x16_bf16(a, bfr, acc, 0, 0, 0);
            }
        }
        // epilogue -> lo (cols = this wave's pixels only)
        #pragma unroll
        for (int r = 0; r < 16; ++r) {
            int mo = (r & 3) + ((r >> 2) << 3) + (kh << 2);
            if (mo < MOFF) lo[mo * 128 + px_i] = acc[r] + b_off[mo];
        }
    }
    __syncthreads();    // cross-half-wave lo visibility

    // ================= Phase B: deform conv (M=64 x N=32 per wave) =========
    float py_r[9], px_r[9];
    #pragma unroll
    for (int t = 0; t < 9; ++t) {
        py_r[t] = (float)(ho - 1 + t / 3) + lo[(2 * t) * 128 + px_i];
        px_r[t] = (float)(px_i - 1 + t % 3) + lo[(2 * t + 1) * 128 + px_i];
    }

    f32x16 acc[2] = {};
    for (int cc = 0; cc < 4; ++cc) {
        const unsigned short* xtc = xt + (size_t)(cc * B_ + b) * PLANE * 16;
        #pragma unroll
        for (int ks = 0; ks < 9; ++ks) {
            float py = py_r[ks], px = px_r[ks];
            float fy = floorf(py), fx = floorf(px);
            float wy = py - fy,    wx = px - fx;
            int y0 = (int)fy, x0 = (int)fx;
            float s[8];
            #pragma unroll
            for (int j = 0; j < 8; ++j) s[j] = 0.f;
            #pragma unroll
            for (int c2 = 0; c2 < 4; ++c2) {
                int yy = y0 + (c2 >> 1);
                int xx = x0 + (c2 & 1);
                bool valid = ((unsigned)yy < (unsigned)H_) && ((unsigned)xx < (unsigned)W_);
                int yc = min(max(yy, 0), H_ - 1);
                int xc = min(max(xx, 0), W_ - 1);
                float wgt = ((c2 >> 1) ? wy : 1.f - wy) * ((c2 & 1) ? wx : 1.f - wx);
                wgt = valid ? wgt : 0.f;
                bf16x8 u = *(const bf16x8*)&xtc[(yc * W_ + xc) * 16 + kh * 8];
                #pragma unroll
                for (int j = 0; j < 8; ++j) s[j] += wgt * bf2f(u[j]);
            }
            bf16x8 v;
            #pragma unroll
            for (int j = 0; j < 8; ++j) v[j] = (short)f2bf(s[j]);
            bf16x8 a0 = *(const bf16x8*)&wbf[m * KTOT + cc * 144 + ks * 16 + kh * 8];
            bf16x8 a1 = *(const bf16x8*)&wbf[(32 + m) * KTOT + cc * 144 + ks * 16 + kh * 8];
            acc[0] = __builtin_amdgcn_mfma_f32_32x32x16_bf16(a0, v, acc[0], 0, 0, 0);
            acc[1] = __builtin_amdgcn_mfma_f32_32x32x16_bf16(a1, v, acc[1], 0, 0, 0);
        }
    }

    // epilogue: col = this lane's pixel, rows = out channels (32x32 layout)
    float* op = out + (size_t)b * O_ * PLANE + ho * WO_ + px_i;
    #pragma unroll
    for (int nt = 0; nt < 2; ++nt) {
        #pragma unroll
        for (int r = 0; r < 16; ++r) {
            int mo = (nt << 5) + (r & 3) + ((r >> 2) << 3) + (kh << 2);
            __builtin_nontemporal_store(acc[nt][r] + bias[mo], op + (size_t)mo * PLANE);
        }
    }
}

// ---------------------------------------------------------------------------
extern "C" void kernel_launch(void* const* d_in, const int* in_sizes, int n_in,
                              void* d_out, int out_size, void* d_ws, size_t ws_size,
                              hipStream_t stream) {
    const float* x     = (const float*)d_in[0];
    const float* w_off = (const float*)d_in[1];
    const float* b_off = (const float*)d_in[2];
    const float* w     = (const float*)d_in[3];
    const float* bias  = (const float*)d_in[4];
    float* out = (float*)d_out;

    unsigned short* wbf  = (unsigned short*)d_ws;                   // 72 KB (tap-major)
    unsigned short* wobf = wbf + O_ * KTOT;                         // 36 KB (tap-major)
    unsigned short* xt   = wobf + 32 * KTOT;                        // 16.78 MB chunk-major

    prep_kernel <<<1024 + 144 + 72, 256, 0, stream>>>(x, w, w_off, xt, wbf, wobf);
    fused_kernel<<<B_ * HO_, 256, 0, stream>>>(xt, wobf, b_off, wbf, bias, out);
}